// Round 4
// baseline (309.291 us; speedup 1.0000x reference)
//
#include <hip/hip_runtime.h>
#include <cstdint>

// N=4096 windows, T=33, C=96, H=6, HD=16.
// ws layout v3:
//   qf  : fp32 q[n][h][t][d]              4096*3168 floats  = 51.9 MB
//         (attn overwrites each window's q region with its output, [t][c] fp32)
//   kvh : bf16 {k,v}[n][s][h][t][d]       4096*6336 ushorts = 51.9 MB
//         (dead after attn; conv_w_proj stashes proj_w B-fragments at its start)
// GEMMs: MFMA 16x16x32 bf16 split-precision (hi+lo): C = AhBh + AlBh + AhBl.
// qkv_w B-fragments precomputed into start of d_out (overwritten by proj later).
// Frag layout: frag fp, lane l, dword d holds bf16x2 of W[k][n],
//   k = kstep*32+(l>>4)*8+2d(+1), n = cf*16+(l&15); dword index = fp*256+l*4+d.

static constexpr int NWIN = 4096;
static constexpr int MROWS = NWIN * 33;          // 135168 = 1056*128
static constexpr float SCALE = 0.25f;            // HD^-0.5

using short8 = __attribute__((ext_vector_type(8))) short;
using f32x4  = __attribute__((ext_vector_type(4))) float;

__device__ __forceinline__ unsigned short f2bf(float f) {
  unsigned u = __float_as_uint(f);
  u += 0x7fffu + ((u >> 16) & 1u);
  return (unsigned short)(u >> 16);
}
__device__ __forceinline__ float bf2f(unsigned short h) {
  return __uint_as_float(((unsigned)h) << 16);
}
// 16 bf16 (32B) -> 16 fp32; even elements from low halves, odd from high.
__device__ __forceinline__ void bfrow16(const unsigned short* p, float* f) {
  const uint4 u0 = *(const uint4*)p;
  const uint4 u1 = *(const uint4*)(p + 8);
  f[0]  = __uint_as_float(u0.x << 16); f[1]  = __uint_as_float(u0.x & 0xffff0000u);
  f[2]  = __uint_as_float(u0.y << 16); f[3]  = __uint_as_float(u0.y & 0xffff0000u);
  f[4]  = __uint_as_float(u0.z << 16); f[5]  = __uint_as_float(u0.z & 0xffff0000u);
  f[6]  = __uint_as_float(u0.w << 16); f[7]  = __uint_as_float(u0.w & 0xffff0000u);
  f[8]  = __uint_as_float(u1.x << 16); f[9]  = __uint_as_float(u1.x & 0xffff0000u);
  f[10] = __uint_as_float(u1.y << 16); f[11] = __uint_as_float(u1.y & 0xffff0000u);
  f[12] = __uint_as_float(u1.z << 16); f[13] = __uint_as_float(u1.z & 0xffff0000u);
  f[14] = __uint_as_float(u1.w << 16); f[15] = __uint_as_float(u1.w & 0xffff0000u);
}

// ---------------- K0: qkv_w -> B-fragments in d_out ----------------
__global__ __launch_bounds__(256) void conv_w_qkv(
    const float* __restrict__ W, unsigned* __restrict__ frag) {
  const int fp = blockIdx.x;                     // 108 = 3 ksteps*18 cf*2 hl
  const int kstep = fp / 36;
  const int r = fp - kstep*36;
  const int cf = r >> 1, hl = r & 1;
  const int t = threadIdx.x, lane = t >> 2, d = t & 3;
  const int k = kstep*32 + (lane >> 4)*8 + d*2;
  const int n = cf*16 + (lane & 15);
  float w0 = W[k*288 + n], w1 = W[(k+1)*288 + n];
  if (hl) { w0 -= bf2f(f2bf(w0)); w1 -= bf2f(f2bf(w1)); }
  frag[fp*256 + t] = (unsigned)f2bf(w0) | ((unsigned)f2bf(w1) << 16);
}

// ---------------- K2b: proj_w -> B-fragments at start of (dead) kvh ----
__global__ __launch_bounds__(256) void conv_w_proj(
    const float* __restrict__ W, unsigned* __restrict__ frag) {
  const int fp = blockIdx.x;                     // 36 = 3 ksteps*6 cf*2 hl
  const int kstep = fp / 12;
  const int r = fp - kstep*12;
  const int cf = r >> 1, hl = r & 1;
  const int t = threadIdx.x, lane = t >> 2, d = t & 3;
  const int k = kstep*32 + (lane >> 4)*8 + d*2;
  const int n = cf*16 + (lane & 15);
  float w0 = W[k*96 + n], w1 = W[(k+1)*96 + n];
  if (hl) { w0 -= bf2f(f2bf(w0)); w1 -= bf2f(f2bf(w1)); }
  frag[fp*256 + t] = (unsigned)f2bf(w0) | ((unsigned)f2bf(w1) << 16);
}

// ---------------- K1: QKV projection, split-bf16 MFMA ----------------
// grid (1056, 3), block 256 (4 waves). s: 0=q (fp32 out), 1=k, 2=v (bf16 out).
__global__ __launch_bounds__(256) void qkv_mfma(
    const float* __restrict__ A, const unsigned* __restrict__ frag,
    const float* __restrict__ bias, float* __restrict__ qf,
    unsigned short* __restrict__ kvh) {
  __shared__ __align__(16) unsigned short sAh[128*104];
  __shared__ __align__(16) unsigned short sAl[128*104];
  const int tid = threadIdx.x;
  const int w = tid >> 6, l = tid & 63;
  const int m0 = blockIdx.x * 128;
  const int s = blockIdx.y;
  for (int idx = tid; idx < 3072; idx += 256) {
    const int row = idx / 24, q = idx - row*24;
    const float4 v = *(const float4*)(A + (size_t)(m0+row)*96 + q*4);
    ushort4 hv, lv;
    hv.x = f2bf(v.x); hv.y = f2bf(v.y); hv.z = f2bf(v.z); hv.w = f2bf(v.w);
    lv.x = f2bf(v.x - bf2f(hv.x)); lv.y = f2bf(v.y - bf2f(hv.y));
    lv.z = f2bf(v.z - bf2f(hv.z)); lv.w = f2bf(v.w - bf2f(hv.w));
    *(ushort4*)&sAh[row*104 + q*4] = hv;
    *(ushort4*)&sAl[row*104 + q*4] = lv;
  }
  __syncthreads();
  f32x4 acc[2][6];
  #pragma unroll
  for (int rf = 0; rf < 2; ++rf)
    #pragma unroll
    for (int cf = 0; cf < 6; ++cf) acc[rf][cf] = (f32x4){0.f,0.f,0.f,0.f};

  #pragma unroll
  for (int kstep = 0; kstep < 3; ++kstep) {
    short8 bh[6], bl[6];
    #pragma unroll
    for (int cf = 0; cf < 6; ++cf) {
      const int fp = (kstep*18 + s*6 + cf)*2;
      bh[cf] = *(const short8*)((const char*)frag + (size_t)fp*1024 + l*16);
      bl[cf] = *(const short8*)((const char*)frag + (size_t)fp*1024 + 1024 + l*16);
    }
    #pragma unroll
    for (int rf = 0; rf < 2; ++rf) {
      const int row = w*32 + rf*16 + (l & 15);
      const int off = row*104 + kstep*32 + (l >> 4)*8;
      const short8 ah = *(const short8*)&sAh[off];
      const short8 al = *(const short8*)&sAl[off];
      #pragma unroll
      for (int cf = 0; cf < 6; ++cf) {
        acc[rf][cf] = __builtin_amdgcn_mfma_f32_16x16x32_bf16(ah, bh[cf], acc[rf][cf], 0,0,0);
        acc[rf][cf] = __builtin_amdgcn_mfma_f32_16x16x32_bf16(al, bh[cf], acc[rf][cf], 0,0,0);
        acc[rf][cf] = __builtin_amdgcn_mfma_f32_16x16x32_bf16(ah, bl[cf], acc[rf][cf], 0,0,0);
      }
    }
  }
  const int col = l & 15;
  if (s == 0) {
    #pragma unroll
    for (int cf = 0; cf < 6; ++cf) {
      const float bv = bias[cf*16 + col];
      #pragma unroll
      for (int rf = 0; rf < 2; ++rf)
        #pragma unroll
        for (int r = 0; r < 4; ++r) {
          const int m = m0 + w*32 + rf*16 + (l >> 4)*4 + r;
          const int n = m / 33, t = m - n*33;
          qf[(size_t)n*3168 + cf*528 + t*16 + col] = (acc[rf][cf][r] + bv)*SCALE;
        }
    }
  } else {
    unsigned short* kvs = kvh + (size_t)(s-1)*3168;
    #pragma unroll
    for (int cf = 0; cf < 6; ++cf) {
      const float bv = bias[s*96 + cf*16 + col];
      #pragma unroll
      for (int rf = 0; rf < 2; ++rf)
        #pragma unroll
        for (int r = 0; r < 4; ++r) {
          const int m = m0 + w*32 + rf*16 + (l >> 4)*4 + r;
          const int n = m / 33, t = m - n*33;
          kvs[(size_t)n*6336 + cf*528 + t*16 + col] = f2bf(acc[rf][cf][r] + bv);
        }
    }
  }
}

// ---------------- K2: per-window attention, bf16 K/V ----------------
// grid 4096, block 256; thread = (head,row), 198 active. LDS 24.9 KB.
__global__ __launch_bounds__(256) void attn_kernel(
    float* __restrict__ qf, const unsigned short* __restrict__ kvh,
    const int* __restrict__ rel, const float* __restrict__ mask,
    const float* __restrict__ rpet) {
  __shared__ __align__(16) unsigned short sKV[6336];  // k[3168] then v[3168]
  __shared__ float sMask[33*33];
  __shared__ unsigned sRelP[32*33];
  __shared__ float sRPE[153*6];
  const int tid = threadIdx.x;
  const int n = blockIdx.x;
  const uint4* kvb = (const uint4*)(kvh + (size_t)n*6336);
  for (int idx = tid; idx < 792; idx += 256) ((uint4*)sKV)[idx] = kvb[idx];
  {
    const int* rb = rel + (size_t)n*3072;
    for (int p = tid; p < 1024; p += 256) {
      const int b = p*3;
      sRelP[(p >> 5)*33 + (p & 31)] =
          (unsigned)rb[b] | ((unsigned)rb[b+1] << 8) | ((unsigned)rb[b+2] << 16);
    }
  }
  for (int idx = tid; idx < 1089; idx += 256)
    sMask[idx] = mask[(size_t)n*1089 + idx];
  for (int idx = tid; idx < 918; idx += 256)
    sRPE[idx] = rpet[idx];

  float qr[16];
  int h = 0, i = 0;
  if (tid < 198) {
    h = tid / 33; i = tid - h*33;
    const float4* qb = (const float4*)(qf + (size_t)n*3168 + h*528 + i*16);
    const float4 t0 = qb[0], t1 = qb[1], t2 = qb[2], t3 = qb[3];
    qr[0]=t0.x; qr[1]=t0.y; qr[2]=t0.z; qr[3]=t0.w;
    qr[4]=t1.x; qr[5]=t1.y; qr[6]=t1.z; qr[7]=t1.w;
    qr[8]=t2.x; qr[9]=t2.y; qr[10]=t2.z; qr[11]=t2.w;
    qr[12]=t3.x; qr[13]=t3.y; qr[14]=t3.z; qr[15]=t3.w;
  }
  __syncthreads();
  if (tid < 198) {
    const float* rph = sRPE + h;
    float p[33];
    float mx = -3.4e38f;
    #pragma unroll
    for (int j = 0; j < 33; ++j) {
      float kf[16];
      bfrow16(&sKV[(h*33 + j)*16], kf);
      float d0 = qr[0]*kf[0], d1 = qr[1]*kf[1], d2 = qr[2]*kf[2], d3 = qr[3]*kf[3];
      #pragma unroll
      for (int d = 4; d < 16; d += 4) {
        d0 = fmaf(qr[d+0], kf[d+0], d0);
        d1 = fmaf(qr[d+1], kf[d+1], d1);
        d2 = fmaf(qr[d+2], kf[d+2], d2);
        d3 = fmaf(qr[d+3], kf[d+3], d3);
      }
      float lo = (d0 + d1) + (d2 + d3) + sMask[i*33 + j];
      if (i > 0 && j > 0) {
        const unsigned pk = sRelP[(i-1)*33 + (j-1)];
        lo += rph[(pk & 0xffu)*6]
            + rph[((pk >> 8) & 0xffu)*6 + 306]
            + rph[((pk >> 16) & 0xffu)*6 + 612];
      }
      p[j] = lo;
      mx = fmaxf(mx, lo);
    }
    float ssum = 0.f;
    #pragma unroll
    for (int j = 0; j < 33; ++j) { p[j] = __expf(p[j] - mx); ssum += p[j]; }
    const float inv = 1.0f / ssum;
    float o[16];
    #pragma unroll
    for (int d = 0; d < 16; ++d) o[d] = 0.f;
    #pragma unroll
    for (int j = 0; j < 33; ++j) {
      float vf[16];
      bfrow16(&sKV[3168 + (h*33 + j)*16], vf);
      const float pj = p[j];
      #pragma unroll
      for (int d = 0; d < 16; ++d) o[d] = fmaf(pj, vf[d], o[d]);
    }
    float* op = qf + (size_t)n*3168 + (size_t)i*96 + h*16;
    float4 r0 = make_float4(o[0]*inv,  o[1]*inv,  o[2]*inv,  o[3]*inv);
    float4 r1 = make_float4(o[4]*inv,  o[5]*inv,  o[6]*inv,  o[7]*inv);
    float4 r2 = make_float4(o[8]*inv,  o[9]*inv,  o[10]*inv, o[11]*inv);
    float4 r3 = make_float4(o[12]*inv, o[13]*inv, o[14]*inv, o[15]*inv);
    *(float4*)(op + 0)  = r0; *(float4*)(op + 4)  = r1;
    *(float4*)(op + 8)  = r2; *(float4*)(op + 12) = r3;
  }
}

// ---------------- K3: output projection, split-bf16 MFMA ----------------
// grid 1056, block 256. A = attn output in qf; B-frags at start of kvh.
__global__ __launch_bounds__(256) void proj_mfma(
    const float* __restrict__ qf, const unsigned* __restrict__ frag,
    const float* __restrict__ bias, float* __restrict__ out) {
  __shared__ __align__(16) unsigned short sAh[128*104];
  __shared__ __align__(16) unsigned short sAl[128*104];
  const int tid = threadIdx.x;
  const int w = tid >> 6, l = tid & 63;
  const int m0 = blockIdx.x * 128;
  for (int idx = tid; idx < 3072; idx += 256) {
    const int row = idx / 24, q = idx - row*24;
    const int m = m0 + row;
    const int n = m / 33, t = m - n*33;
    const float4 v = *(const float4*)(qf + (size_t)n*3168 + t*96 + q*4);
    ushort4 hv, lv;
    hv.x = f2bf(v.x); hv.y = f2bf(v.y); hv.z = f2bf(v.z); hv.w = f2bf(v.w);
    lv.x = f2bf(v.x - bf2f(hv.x)); lv.y = f2bf(v.y - bf2f(hv.y));
    lv.z = f2bf(v.z - bf2f(hv.z)); lv.w = f2bf(v.w - bf2f(hv.w));
    *(ushort4*)&sAh[row*104 + q*4] = hv;
    *(ushort4*)&sAl[row*104 + q*4] = lv;
  }
  __syncthreads();
  f32x4 acc[2][6];
  #pragma unroll
  for (int rf = 0; rf < 2; ++rf)
    #pragma unroll
    for (int cf = 0; cf < 6; ++cf) acc[rf][cf] = (f32x4){0.f,0.f,0.f,0.f};

  #pragma unroll
  for (int kstep = 0; kstep < 3; ++kstep) {
    short8 bh[6], bl[6];
    #pragma unroll
    for (int cf = 0; cf < 6; ++cf) {
      const int fph = kstep*12 + cf*2;
      bh[cf] = *(const short8*)(frag + fph*256 + l*4);
      bl[cf] = *(const short8*)(frag + (fph+1)*256 + l*4);
    }
    #pragma unroll
    for (int rf = 0; rf < 2; ++rf) {
      const int row = w*32 + rf*16 + (l & 15);
      const int off = row*104 + kstep*32 + (l >> 4)*8;
      const short8 ah = *(const short8*)&sAh[off];
      const short8 al = *(const short8*)&sAl[off];
      #pragma unroll
      for (int cf = 0; cf < 6; ++cf) {
        acc[rf][cf] = __builtin_amdgcn_mfma_f32_16x16x32_bf16(ah, bh[cf], acc[rf][cf], 0,0,0);
        acc[rf][cf] = __builtin_amdgcn_mfma_f32_16x16x32_bf16(al, bh[cf], acc[rf][cf], 0,0,0);
        acc[rf][cf] = __builtin_amdgcn_mfma_f32_16x16x32_bf16(ah, bl[cf], acc[rf][cf], 0,0,0);
      }
    }
  }
  const int col = l & 15;
  #pragma unroll
  for (int cf = 0; cf < 6; ++cf) {
    const float bv = bias[cf*16 + col];
    #pragma unroll
    for (int rf = 0; rf < 2; ++rf)
      #pragma unroll
      for (int r = 0; r < 4; ++r) {
        const int m = m0 + w*32 + rf*16 + (l >> 4)*4 + r;
        out[(size_t)m*96 + cf*16 + col] = acc[rf][cf][r] + bv;
      }
  }
}

extern "C" void kernel_launch(void* const* d_in, const int* in_sizes, int n_in,
                              void* d_out, int out_size, void* d_ws, size_t ws_size,
                              hipStream_t stream) {
  const float* data   = (const float*)d_in[0];
  const int*   rel    = (const int*)  d_in[1];
  const float* mask   = (const float*)d_in[2];
  const float* qkv_w  = (const float*)d_in[3];
  const float* qkv_b  = (const float*)d_in[4];
  const float* proj_w = (const float*)d_in[5];
  const float* proj_b = (const float*)d_in[6];
  const float* rpet   = (const float*)d_in[7];
  float* qf = (float*)d_ws;                              // 51.9 MB
  unsigned short* kvh = (unsigned short*)(qf + (size_t)NWIN*3168);  // 51.9 MB
  float* out = (float*)d_out;

  conv_w_qkv <<<dim3(108),         256, 0, stream>>>(qkv_w, (unsigned*)d_out);
  qkv_mfma   <<<dim3(MROWS/128,3), 256, 0, stream>>>(data, (const unsigned*)d_out, qkv_b, qf, kvh);
  attn_kernel<<<dim3(NWIN),        256, 0, stream>>>(qf, kvh, rel, mask, rpet);
  conv_w_proj<<<dim3(36),          256, 0, stream>>>(proj_w, (unsigned*)kvh);
  proj_mfma  <<<dim3(MROWS/128),   256, 0, stream>>>(qf, (const unsigned*)kvh, proj_b, out);
}